// Round 8
// baseline (68.279 us; speedup 1.0000x reference)
//
#include <hip/hip_runtime.h>

#define N        8192   // 8*32*32  (DEPTH=8, LENGTH=32, WIDTH=32)
#define NCLS     8
#define ROWS_PB  4                 // one wave (64 lanes) per row, 4 rows per block
#define TPB      256
#define GRID     (N / ROWS_PB)     // 2048 blocks = 8 blocks/CU = 32 waves/CU (full TLP)
#define GROUPS   64                // two-level ticket: 64 groups x 32 blocks
#define GPB      (GRID / GROUPS)   // 32

#define GP_DW    32768             // group partials: 64 x 16 dwords
#define L1_DW    34816             // 64 counters, 128B (32-dword) stride: own lines
#define L2_DW    36864             // level-2 counter, own 128B line
#define BASE_DW  36992             // never-written dword, same 64B fill phase

// Single dispatch, zero fences. R7 post-mortem: R5-R7's reuse/ILP restructures
// cut occupancy to 2-4 waves/SIMD and the latency-bound gather paid ~9us for
// it; R0's geometry (2048x256, one row/wave, 8 waves/SIMD) ran the same math
// in ~4.5us. This round: R0's full-TLP compute (bit-identical math, absmax
// 0.0) + register double-buffer (load k+1 during compute k; ~50 VGPR keeps
// 8 waves/SIMD) inside the R5-validated fence-free single-dispatch shell.
//
// Three-stage fence-free reduction:
//   block  -> UC-store 16-dword partial row        (2048 rows)
//   group-last (ticket L1, 64 groups x 32) -> folds its group's 32 rows ->
//              UC-store group row -> s_waitcnt vmcnt(0) -> ticket L2
//   global-last (ticket L2) -> folds 64 group rows in one wave -> loss
//
// Ticket (validated R3-R7): d_ws re-poisoned by a periodic (<=64B) fill;
// BASE_DW (never written, same 64B phase) supplies every counter's initial
// value; (old - base) mod groupsize counts prior increments; survives rocprof
// replay. UC ops (RELAXED/AGENT -> sc0 sc1) complete at the coherence point;
// __syncthreads()/s_waitcnt vmcnt(0) drain before each ticket bump orders the
// handoff without any cache-writeback fence.
__global__ __launch_bounds__(TPB) void sncut_fused(const float* __restrict__ f,
                                                   const float* __restrict__ P,
                                                   float* __restrict__ ws,
                                                   float* __restrict__ out)
{
    const int tid  = threadIdx.x;
    const int lane = tid & 63;
    const int wave = tid >> 6;
    const int i    = blockIdx.x * ROWS_PB + wave;

    const int zi = i & 31, yi = (i >> 5) & 31, xi = i >> 10;
    const float fi = f[i];

    float v0 = 0.f, v1 = 0.f, v2 = 0.f, v3 = 0.f;
    float v4 = 0.f, v5 = 0.f, v6 = 0.f, v7 = 0.f;
    float vr = 0.f;

    if (lane < 63) {
        const int oy = lane / 9, oz = lane - oy * 9;   // 7 x 9 = 63 lanes

        int y0 = yi - 3; y0 = y0 < 0 ? 0 : (y0 > 25 ? 25 : y0);
        int z0 = zi - 4; z0 = z0 < 0 ? 0 : (z0 > 23 ? 23 : z0);
        int x0 = xi - 3; x0 = x0 < 0 ? 0 : (x0 > 1 ? 1 : x0);

        const int yj = y0 + oy, zj = z0 + oz;
        const int dy = yi - yj, dz = zi - zj;
        const float base = (float)(dy * dy + dz * dz);
        const int jcol = (yj << 5) + zj;

        // register double-buffer: load k+1 while computing k (static indices)
        int j = (x0 << 10) + jcol;
        float  fjA = f[j];
        float4 p0A = *reinterpret_cast<const float4*>(P + (size_t)j * NCLS);
        float4 p1A = *reinterpret_cast<const float4*>(P + (size_t)j * NCLS + 4);

        #pragma unroll
        for (int k = 0; k < 7; ++k) {
            float fjN; float4 p0N, p1N;
            if (k < 6) {
                const int jn = ((x0 + k + 1) << 10) + jcol;
                fjN = f[jn];
                p0N = *reinterpret_cast<const float4*>(P + (size_t)jn * NCLS);
                p1N = *reinterpret_cast<const float4*>(P + (size_t)jn * NCLS + 4);
            }
            const int dx = xi - (x0 + k);
            const float df  = fi - fjA;
            const float arg = df * df * (1.0f / 9.0f) + (base + (float)(dx * dx));
            const float w   = __expf(-arg);
            v0 += w * p0A.x; v1 += w * p0A.y; v2 += w * p0A.z; v3 += w * p0A.w;
            v4 += w * p1A.x; v5 += w * p1A.y; v6 += w * p1A.z; v7 += w * p1A.w;
            vr += w;
            if (k < 6) { fjA = fjN; p0A = p0N; p1A = p1N; }
        }
    }

    // ---- wave reduction (result lands in lane 0)
    float vals[9] = {v0, v1, v2, v3, v4, v5, v6, v7, vr};
    #pragma unroll
    for (int v = 0; v < 9; ++v) {
        float x = vals[v];
        #pragma unroll
        for (int off = 32; off > 0; off >>= 1)
            x += __shfl_down(x, off, 64);
        vals[v] = x;
    }

    // ---- per-row 16-entry contribution into LDS, fold 4 waves, one UC store
    __shared__ float sh[ROWS_PB][16];
    if (lane == 0) {
        const float4 p0 = *reinterpret_cast<const float4*>(P + (size_t)i * NCLS);
        const float4 p1 = *reinterpret_cast<const float4*>(P + (size_t)i * NCLS + 4);
        sh[wave][0]  = p0.x * vals[0];
        sh[wave][1]  = p0.y * vals[1];
        sh[wave][2]  = p0.z * vals[2];
        sh[wave][3]  = p0.w * vals[3];
        sh[wave][4]  = p1.x * vals[4];
        sh[wave][5]  = p1.y * vals[5];
        sh[wave][6]  = p1.z * vals[6];
        sh[wave][7]  = p1.w * vals[7];
        sh[wave][8]  = p0.x * vals[8];
        sh[wave][9]  = p0.y * vals[8];
        sh[wave][10] = p0.z * vals[8];
        sh[wave][11] = p0.w * vals[8];
        sh[wave][12] = p1.x * vals[8];
        sh[wave][13] = p1.y * vals[8];
        sh[wave][14] = p1.z * vals[8];
        sh[wave][15] = p1.w * vals[8];
    }
    __syncthreads();
    if (tid < 16) {
        const float s = sh[0][tid] + sh[1][tid] + sh[2][tid] + sh[3][tid];
        __hip_atomic_store(&ws[(size_t)blockIdx.x * 16 + tid], s,
                           __ATOMIC_RELAXED, __HIP_MEMORY_SCOPE_AGENT);
    }

    // ---- ticket level 1 (relaxed, no fences)
    __shared__ int flag1;
    __shared__ unsigned int sbase;
    __syncthreads();   // drains vmcnt(0): UC stores completed at coherence point
    if (tid == 0) {
        unsigned int* w32 = (unsigned int*)ws;
        const unsigned int pbase =
            __hip_atomic_load(w32 + BASE_DW, __ATOMIC_RELAXED, __HIP_MEMORY_SCOPE_AGENT);
        sbase = pbase;
        const int grp = blockIdx.x >> 5;               // /GPB, 0..63
        const unsigned int o1 =
            __hip_atomic_fetch_add(w32 + L1_DW + grp * 32, 1u,
                                   __ATOMIC_RELAXED, __HIP_MEMORY_SCOPE_AGENT);
        flag1 = (((o1 - pbase) & (unsigned int)(GPB - 1)) == (unsigned int)(GPB - 1));
    }
    __syncthreads();
    if (!flag1 || wave != 0) return;

    // ---- group-last (wave 0 only): fold this group's 32 partial rows
    {
        const int grp = blockIdx.x >> 5;
        if (lane < 16) {
            float gsum = 0.f;
            #pragma unroll
            for (int m = 0; m < GPB; ++m)
                gsum += __hip_atomic_load(&ws[(size_t)(grp * GPB + m) * 16 + lane],
                                          __ATOMIC_RELAXED, __HIP_MEMORY_SCOPE_AGENT);
            __hip_atomic_store(&ws[GP_DW + (size_t)grp * 16 + lane], gsum,
                               __ATOMIC_RELAXED, __HIP_MEMORY_SCOPE_AGENT);
        }
        asm volatile("s_waitcnt vmcnt(0)" ::: "memory");   // group row at coherence pt

        int gl = 0;
        if (lane == 0) {
            unsigned int* w32 = (unsigned int*)ws;
            const unsigned int o2 =
                __hip_atomic_fetch_add(w32 + L2_DW, 1u,
                                       __ATOMIC_RELAXED, __HIP_MEMORY_SCOPE_AGENT);
            gl = (((o2 - sbase) & (unsigned int)(GROUPS - 1)) == (unsigned int)(GROUPS - 1));
        }
        gl = __shfl(gl, 0, 64);
        if (!gl) return;

        // ---- global-last wave: fold 64 group rows -> 16 sums -> loss
        const int e = lane & 15, q = lane >> 4;        // 4 quarters x 16 entries
        float s = 0.f;
        #pragma unroll
        for (int gg = 0; gg < GROUPS / 4; ++gg)        // 16 loads per lane
            s += __hip_atomic_load(&ws[GP_DW + (size_t)(q + gg * 4) * 16 + e],
                                   __ATOMIC_RELAXED, __HIP_MEMORY_SCOPE_AGENT);
        s += __shfl_down(s, 32, 64);
        s += __shfl_down(s, 16, 64);                   // lanes 0..15: per-e totals

        // lanes 0..7: num/den ratio; fold ratios to lane 0
        float r = s / __shfl_down(s, 8, 64);           // junk in lanes>=8, finite
        r += __shfl_down(r, 4, 64);
        r += __shfl_down(r, 2, 64);
        r += __shfl_down(r, 1, 64);
        if (lane == 0) out[0] = (float)NCLS - r;
    }
}

extern "C" void kernel_launch(void* const* d_in, const int* in_sizes, int n_in,
                              void* d_out, int out_size, void* d_ws, size_t ws_size,
                              hipStream_t stream) {
    const float* f = (const float*)d_in[0];   // patch, 8192 fp32
    const float* P = (const float*)d_in[1];   // prob, 8192x8 fp32
    // d_in[2] is k==8 (compile-time constant here)

    sncut_fused<<<GRID, TPB, 0, stream>>>(f, P, (float*)d_ws, (float*)d_out);
}

// Round 9
// 64.754 us; speedup vs baseline: 1.0544x; 1.0544x over previous
//
#include <hip/hip_runtime.h>

#define N        8192   // 8*32*32  (DEPTH=8, LENGTH=32, WIDTH=32)
#define NCLS     8
#define TPB      64                // ONE wave per block
#define GRID     512               // 2 x-halves * 256 (y,z) quads
#define GROUPS   32                // two-level ticket: 32 groups x 16 blocks
#define GPB      (GRID / GROUPS)   // 16

#define GP_DW    8192              // group partials: 32 x 16 dwords (after 512x16 rows)
#define L1_DW    16384             // 32 counters, 128B (32-dword) stride: own lines
#define L2_DW    17472             // level-2 counter, own 128B line
#define BASE_DW  17536             // never-written dword, same 64B fill phase

// Single dispatch, zero fences. R8 post-mortem: overhead is ~10us FIXED per
// iteration + ~1us per dispatch (refit of R0/R3/R5-R8); the fused kernel is
// gather-instruction-bound (VALUBusy ~5%). Every win so far cut gather insts
// or exposures (R6 quad, R7 prefetch); R8's per-row geometry maximized them
// and regressed. This round: X-FUSION. Window slabs are identical for
// xi in {0..3} (slabs 0..6) and for xi in {4..7} (slabs 1..7), so one wave
// loads 7 slabs ONCE and serves 16 centers (4 xi * 2x2 yz): 4x fewer gather
// insts than R7 (43K -> 10.7K total). VALU rises to ~1800 inst/wave ~ 1.5us
// wall at 512 waves (2/CU) -- inside the 6x VALU headroom.
//
// Linearity trick: num_t = sum_i P[i,t]*(sum_lanes partial_{i,t,lane}) --
// the P[i,t] multiply distributes over the lane-sum, so each lane contracts
// its OWN partials with P[i,t] first, and only 16 values cross lanes
// (16 shuffle chains instead of 144; no LDS fold, no __syncthreads).
//
// Accuracy: per-center window identical to R6/R7 (absmax 0.0): full +-3 y/z
// (8-wide quad union, clamp-shifted), exact 7-slab x window per center
// (verified: half 0 -> all windows = slabs 0..6; half 1 -> slabs 1..7).
// Only fp summation order changes (error ~1e-6 << 7.4e-2 threshold).
//
// Ticket (validated R3-R8): d_ws re-poisoned by a periodic (<=64B) fill;
// BASE_DW (never written, same 64B phase) supplies every counter's initial
// value; (old - base) mod groupsize counts prior increments; survives
// rocprof replay. UC ops (RELAXED/AGENT -> sc0 sc1) complete at the
// coherence point; s_waitcnt vmcnt(0) before each ticket bump orders the
// handoff with no cache-writeback fence. 3-stage fold: block row ->
// group-last folds 16 rows -> global-last folds 32 group rows -> loss.
__global__ __launch_bounds__(TPB) void sncut_fused(const float* __restrict__ f,
                                                   const float* __restrict__ P,
                                                   float* __restrict__ ws,
                                                   float* __restrict__ out)
{
    const int lane = threadIdx.x;          // single wave per block
    const int b    = blockIdx.x;
    const int half = b >> 8;               // 0: xi 0..3, slabs 0..6 | 1: xi 4..7, slabs 1..7
    const int rem  = b & 255;
    const int yi   = ((rem >> 4) & 15) << 1;   // even, 0..30
    const int zi   = (rem & 15) << 1;          // even, 0..30

    int Y0 = yi - 3; Y0 = Y0 < 0 ? 0 : (Y0 > 24 ? 24 : Y0);   // 8-wide y union
    int Z0 = zi - 3; Z0 = Z0 < 0 ? 0 : (Z0 > 24 ? 24 : Z0);   // 8-wide z union
    const int X0 = half;                   // 7 slabs X0..X0+6

    const int oy = lane >> 3, oz = lane & 7;                  // 8x8 = 64 lanes
    const int yj = Y0 + oy, zj = Z0 + oz;
    const int jcol = (yj << 5) + zj;

    // ---- PREFETCH: 7 slabs x {f, P.lo, P.hi} = 21 gathers, one wait covers all
    float  fjv[7];
    float4 p0v[7], p1v[7];
    #pragma unroll
    for (int k = 0; k < 7; ++k) {
        const int j = ((X0 + k) << 10) + jcol;
        fjv[k] = f[j];
        p0v[k] = *reinterpret_cast<const float4*>(P + (size_t)j * NCLS);
        p1v[k] = *reinterpret_cast<const float4*>(P + (size_t)j * NCLS + 4);
    }

    // ---- 16 center f values (uniform broadcast loads)
    float fic[4][4];
    #pragma unroll
    for (int cx = 0; cx < 4; ++cx) {
        const int ib = ((half * 4 + cx) << 10) + (yi << 5) + zi;
        fic[cx][0] = f[ib];      fic[cx][1] = f[ib + 1];
        fic[cx][2] = f[ib + 32]; fic[cx][3] = f[ib + 33];
    }

    const float dy0 = (float)(yi - yj),     dy1 = (float)(yi + 1 - yj);
    const float dz0 = (float)(zi - zj),     dz1 = (float)(zi + 1 - zj);
    const float byz[4] = { dy0 * dy0 + dz0 * dz0, dy0 * dy0 + dz1 * dz1,
                           dy1 * dy1 + dz0 * dz0, dy1 * dy1 + dz1 * dz1 };

    float r16[16];
    #pragma unroll
    for (int e = 0; e < 16; ++e) r16[e] = 0.f;

    #pragma unroll
    for (int cx = 0; cx < 4; ++cx) {
        float vv[4][9];
        #pragma unroll
        for (int c = 0; c < 4; ++c)
            #pragma unroll
            for (int t = 0; t < 9; ++t) vv[c][t] = 0.f;

        #pragma unroll
        for (int k = 0; k < 7; ++k) {
            const int dx = 3 * half + cx - k;        // xi - xj
            const float dx2 = (float)(dx * dx);
            const float fj  = fjv[k];
            const float4 p0 = p0v[k];
            const float4 p1 = p1v[k];
            #pragma unroll
            for (int c = 0; c < 4; ++c) {
                const float df = fic[cx][c] - fj;
                const float w  = __expf(-(df * df * (1.0f / 9.0f) + byz[c] + dx2));
                vv[c][0] += w * p0.x; vv[c][1] += w * p0.y;
                vv[c][2] += w * p0.z; vv[c][3] += w * p0.w;
                vv[c][4] += w * p1.x; vv[c][5] += w * p1.y;
                vv[c][6] += w * p1.z; vv[c][7] += w * p1.w;
                vv[c][8] += w;
            }
        }

        // per-lane contraction with P[i_c] (linearity: distributes over lane-sum)
        #pragma unroll
        for (int c = 0; c < 4; ++c) {
            const int ic = ((half * 4 + cx) << 10) + ((yi + (c >> 1)) << 5) + (zi + (c & 1));
            const float4 q0 = *reinterpret_cast<const float4*>(P + (size_t)ic * NCLS);
            const float4 q1 = *reinterpret_cast<const float4*>(P + (size_t)ic * NCLS + 4);
            r16[0]  += q0.x * vv[c][0]; r16[1]  += q0.y * vv[c][1];
            r16[2]  += q0.z * vv[c][2]; r16[3]  += q0.w * vv[c][3];
            r16[4]  += q1.x * vv[c][4]; r16[5]  += q1.y * vv[c][5];
            r16[6]  += q1.z * vv[c][6]; r16[7]  += q1.w * vv[c][7];
            r16[8]  += q0.x * vv[c][8]; r16[9]  += q0.y * vv[c][8];
            r16[10] += q0.z * vv[c][8]; r16[11] += q0.w * vv[c][8];
            r16[12] += q1.x * vv[c][8]; r16[13] += q1.y * vv[c][8];
            r16[14] += q1.z * vv[c][8]; r16[15] += q1.w * vv[c][8];
        }
    }

    // ---- wave reduction: 16 chains (totals land in lane 0)
    #pragma unroll
    for (int e = 0; e < 16; ++e) {
        float x = r16[e];
        #pragma unroll
        for (int off = 32; off > 0; off >>= 1)
            x += __shfl_down(x, off, 64);
        r16[e] = x;
    }

    // ---- block partial row: 16 UC stores from lane 0
    if (lane == 0) {
        #pragma unroll
        for (int e = 0; e < 16; ++e)
            __hip_atomic_store(&ws[(size_t)b * 16 + e], r16[e],
                               __ATOMIC_RELAXED, __HIP_MEMORY_SCOPE_AGENT);
    }
    asm volatile("s_waitcnt vmcnt(0)" ::: "memory");   // row at coherence point

    // ---- ticket level 1 (relaxed, no fences)
    unsigned int pbase = 0u;
    int fl = 0;
    if (lane == 0) {
        unsigned int* w32 = (unsigned int*)ws;
        pbase = __hip_atomic_load(w32 + BASE_DW, __ATOMIC_RELAXED, __HIP_MEMORY_SCOPE_AGENT);
        const unsigned int o1 =
            __hip_atomic_fetch_add(w32 + L1_DW + (b >> 4) * 32, 1u,
                                   __ATOMIC_RELAXED, __HIP_MEMORY_SCOPE_AGENT);
        fl = (((o1 - pbase) & (unsigned int)(GPB - 1)) == (unsigned int)(GPB - 1));
    }
    fl = __shfl(fl, 0, 64);
    if (!fl) return;

    // ---- group-last wave: fold this group's 16 rows -> group row
    const int grp = b >> 4;
    const int e = lane & 15, q = lane >> 4;            // 4 quarters x 16 entries
    float s = 0.f;
    #pragma unroll
    for (int mm = 0; mm < 4; ++mm)
        s += __hip_atomic_load(&ws[(size_t)(grp * GPB + q + mm * 4) * 16 + e],
                               __ATOMIC_RELAXED, __HIP_MEMORY_SCOPE_AGENT);
    s += __shfl_down(s, 32, 64);
    s += __shfl_down(s, 16, 64);                       // lanes 0..15: group sums
    if (lane < 16)
        __hip_atomic_store(&ws[GP_DW + (size_t)grp * 16 + lane], s,
                           __ATOMIC_RELAXED, __HIP_MEMORY_SCOPE_AGENT);
    asm volatile("s_waitcnt vmcnt(0)" ::: "memory");   // group row at coherence pt

    int gl = 0;
    if (lane == 0) {
        unsigned int* w32 = (unsigned int*)ws;
        const unsigned int o2 =
            __hip_atomic_fetch_add(w32 + L2_DW, 1u,
                                   __ATOMIC_RELAXED, __HIP_MEMORY_SCOPE_AGENT);
        gl = (((o2 - pbase) & (unsigned int)(GROUPS - 1)) == (unsigned int)(GROUPS - 1));
    }
    gl = __shfl(gl, 0, 64);
    if (!gl) return;

    // ---- global-last wave: fold 32 group rows -> 16 sums -> loss
    float s2 = 0.f;
    #pragma unroll
    for (int mm = 0; mm < 8; ++mm)
        s2 += __hip_atomic_load(&ws[GP_DW + (size_t)(q + mm * 4) * 16 + e],
                                __ATOMIC_RELAXED, __HIP_MEMORY_SCOPE_AGENT);
    s2 += __shfl_down(s2, 32, 64);
    s2 += __shfl_down(s2, 16, 64);                     // lanes 0..15: per-e totals

    // lanes 0..7: num/den ratios; fold to lane 0 (R7-validated tail)
    float r = s2 / __shfl_down(s2, 8, 64);             // junk in lanes>=8, discarded
    r += __shfl_down(r, 4, 64);
    r += __shfl_down(r, 2, 64);
    r += __shfl_down(r, 1, 64);
    if (lane == 0) out[0] = (float)NCLS - r;
}

extern "C" void kernel_launch(void* const* d_in, const int* in_sizes, int n_in,
                              void* d_out, int out_size, void* d_ws, size_t ws_size,
                              hipStream_t stream) {
    const float* f = (const float*)d_in[0];   // patch, 8192 fp32
    const float* P = (const float*)d_in[1];   // prob, 8192x8 fp32
    // d_in[2] is k==8 (compile-time constant here)

    sncut_fused<<<GRID, TPB, 0, stream>>>(f, P, (float*)d_ws, (float*)d_out);
}

// Round 10
// 62.098 us; speedup vs baseline: 1.0995x; 1.0428x over previous
//
#include <hip/hip_runtime.h>

#define N        8192   // 8*32*32  (DEPTH=8, LENGTH=32, WIDTH=32)
#define NCLS     8
#define QUADS    2048              // one wave per 2x2 (y,z) quad of centers
#define WAVES_PB 8                 // 8 quads (32 rows) per block
#define TPB      512
#define GRID     (QUADS / WAVES_PB)   // 256 blocks (1 per CU -- minimum useful)
#define GROUPS   16                // two-level ticket: 16 groups x 16 blocks
#define GPB      (GRID / GROUPS)   // 16

#define L1_DW    16384             // 16 counters, 128B (32-dword) stride: own lines
#define L2_DW    16896             // level-2 counter, own 128B line
#define BASE_DW  16960             // never-written dword, same 64B fill phase

// FINAL: revert to the best-measured configuration (R7, 63.85us) + the
// R9-validated linearity contraction.
//
// Session findings driving this shape:
//  - single dispatch, ZERO fences (R4: per-block __threadfence = buffer_wbl2
//    storm, ~27us; R5's UC-store/relaxed-ticket shell removed it);
//  - kernel time tracks BLOCK COUNT (~2-3ns/block of coherence-point traffic:
//    256 blk -> 13us, 512 -> 14-16us, 2048 -> 17.6us); 256 blocks = 1/CU is
//    the minimum that keeps all CUs busy -> R7 geometry is optimal;
//  - occupancy (R8) and gather-count (R9) theories falsified; prefetch (R7,
//    -1.65us) and quad reuse (R6, -1.5us) are the real compute levers, both here;
//  - linearity: num_t = sum_i P[i,t]*(lane-sum) distributes, so each lane
//    contracts its OWN partials with the 4 center-P rows first -> 16 shuffle
//    chains instead of 36 (R9 validated, absmax 0.0).
//
// Accuracy: per-center window = full +-3 y/z (8-wide quad union clamp-shifted)
// x clamp-shifted x+-3 (7 slabs); dropped terms <= exp(-16) ~ 1e-7; measured
// absmax 0.0 for this window across R0-R9.
//
// Ticket (validated R3-R9): d_ws is re-poisoned by a periodic (<=64B) pattern
// fill; BASE_DW (never written, same 64B phase) holds every counter's initial
// value; (old - base) mod groupsize counts prior increments; survives rocprof
// replay. UC ops (RELAXED/AGENT -> sc0 sc1) complete at the coherence point;
// __syncthreads() drains vmcnt(0) before the ticket bump -> ordered handoff
// with no cache-writeback fence anywhere.
__global__ __launch_bounds__(TPB, 2) void sncut_fused(const float* __restrict__ f,
                                                      const float* __restrict__ P,
                                                      float* __restrict__ ws,
                                                      float* __restrict__ out)
{
    const int tid  = threadIdx.x;
    const int lane = tid & 63;
    const int wave = tid >> 6;
    const int q    = blockIdx.x * WAVES_PB + wave;   // quad id 0..2047

    const int xi  = q >> 8;               // 0..7
    const int rem = q & 255;
    const int yi  = (rem >> 4) << 1;      // even, 0..30
    const int zi  = (rem & 15) << 1;      // even, 0..30

    // 4 centers: c = cy*2+cz -> (xi, yi+cy, zi+cz)
    const int ibase = (xi << 10) + (yi << 5) + zi;
    const float fi00 = f[ibase];
    const float fi01 = f[ibase + 1];
    const float fi10 = f[ibase + 32];
    const float fi11 = f[ibase + 33];

    int Y0 = yi - 3; Y0 = Y0 < 0 ? 0 : (Y0 > 24 ? 24 : Y0);   // 8-wide y union
    int Z0 = zi - 3; Z0 = Z0 < 0 ? 0 : (Z0 > 24 ? 24 : Z0);   // 8-wide z union
    int X0 = xi - 3; X0 = X0 < 0 ? 0 : (X0 > 1 ? 1 : X0);     // 7-wide x window

    const int oy = lane >> 3, oz = lane & 7;                  // 8x8 = 64 lanes
    const int yj = Y0 + oy, zj = Z0 + oz;
    const int jcol = (yj << 5) + zj;

    const float dy0 = (float)(yi - yj),     dy1 = (float)(yi + 1 - yj);
    const float dz0 = (float)(zi - zj),     dz1 = (float)(zi + 1 - zj);
    const float b00 = dy0 * dy0 + dz0 * dz0;
    const float b01 = dy0 * dy0 + dz1 * dz1;
    const float b10 = dy1 * dy1 + dz0 * dz0;
    const float b11 = dy1 * dy1 + dz1 * dz1;

    // ---- PREFETCH: 21 window gathers + 8 uniform center-P rows, one wait
    float  fjv[7];
    float4 p0v[7], p1v[7];
    #pragma unroll
    for (int k = 0; k < 7; ++k) {
        const int j = ((X0 + k) << 10) + jcol;
        fjv[k] = f[j];
        p0v[k] = *reinterpret_cast<const float4*>(P + (size_t)j * NCLS);
        p1v[k] = *reinterpret_cast<const float4*>(P + (size_t)j * NCLS + 4);
    }
    float4 pc0[4], pc1[4];                 // center-P rows, all lanes (broadcast)
    {
        const int ic[4] = {ibase, ibase + 1, ibase + 32, ibase + 33};
        #pragma unroll
        for (int c = 0; c < 4; ++c) {
            pc0[c] = *reinterpret_cast<const float4*>(P + (size_t)ic[c] * NCLS);
            pc1[c] = *reinterpret_cast<const float4*>(P + (size_t)ic[c] * NCLS + 4);
        }
    }

    float vv[4][9];
    #pragma unroll
    for (int c = 0; c < 4; ++c)
        #pragma unroll
        for (int t = 0; t < 9; ++t) vv[c][t] = 0.f;

    #pragma unroll
    for (int k = 0; k < 7; ++k) {
        const int dx = xi - (X0 + k);
        const float dx2 = (float)(dx * dx);
        const float fj  = fjv[k];
        const float4 p0 = p0v[k];
        const float4 p1 = p1v[k];

        float df, w;
        df = fi00 - fj; w = __expf(-(df * df * (1.0f / 9.0f) + b00 + dx2));
        vv[0][0] += w * p0.x; vv[0][1] += w * p0.y; vv[0][2] += w * p0.z; vv[0][3] += w * p0.w;
        vv[0][4] += w * p1.x; vv[0][5] += w * p1.y; vv[0][6] += w * p1.z; vv[0][7] += w * p1.w;
        vv[0][8] += w;
        df = fi01 - fj; w = __expf(-(df * df * (1.0f / 9.0f) + b01 + dx2));
        vv[1][0] += w * p0.x; vv[1][1] += w * p0.y; vv[1][2] += w * p0.z; vv[1][3] += w * p0.w;
        vv[1][4] += w * p1.x; vv[1][5] += w * p1.y; vv[1][6] += w * p1.z; vv[1][7] += w * p1.w;
        vv[1][8] += w;
        df = fi10 - fj; w = __expf(-(df * df * (1.0f / 9.0f) + b10 + dx2));
        vv[2][0] += w * p0.x; vv[2][1] += w * p0.y; vv[2][2] += w * p0.z; vv[2][3] += w * p0.w;
        vv[2][4] += w * p1.x; vv[2][5] += w * p1.y; vv[2][6] += w * p1.z; vv[2][7] += w * p1.w;
        vv[2][8] += w;
        df = fi11 - fj; w = __expf(-(df * df * (1.0f / 9.0f) + b11 + dx2));
        vv[3][0] += w * p0.x; vv[3][1] += w * p0.y; vv[3][2] += w * p0.z; vv[3][3] += w * p0.w;
        vv[3][4] += w * p1.x; vv[3][5] += w * p1.y; vv[3][6] += w * p1.z; vv[3][7] += w * p1.w;
        vv[3][8] += w;
    }

    // ---- per-lane linearity contraction (R9-validated): 16 values cross lanes
    float r16[16];
    #pragma unroll
    for (int e = 0; e < 16; ++e) r16[e] = 0.f;
    #pragma unroll
    for (int c = 0; c < 4; ++c) {
        r16[0]  += pc0[c].x * vv[c][0]; r16[1]  += pc0[c].y * vv[c][1];
        r16[2]  += pc0[c].z * vv[c][2]; r16[3]  += pc0[c].w * vv[c][3];
        r16[4]  += pc1[c].x * vv[c][4]; r16[5]  += pc1[c].y * vv[c][5];
        r16[6]  += pc1[c].z * vv[c][6]; r16[7]  += pc1[c].w * vv[c][7];
        r16[8]  += pc0[c].x * vv[c][8]; r16[9]  += pc0[c].y * vv[c][8];
        r16[10] += pc0[c].z * vv[c][8]; r16[11] += pc0[c].w * vv[c][8];
        r16[12] += pc1[c].x * vv[c][8]; r16[13] += pc1[c].y * vv[c][8];
        r16[14] += pc1[c].z * vv[c][8]; r16[15] += pc1[c].w * vv[c][8];
    }

    // ---- wave reduction: 16 chains (totals land in lane 0)
    #pragma unroll
    for (int e = 0; e < 16; ++e) {
        float x = r16[e];
        #pragma unroll
        for (int off = 32; off > 0; off >>= 1)
            x += __shfl_down(x, off, 64);
        r16[e] = x;
    }

    // ---- fold 8 waves in LDS, one UC partial row per block
    __shared__ float sh[WAVES_PB][16];
    if (lane == 0) {
        #pragma unroll
        for (int e = 0; e < 16; ++e) sh[wave][e] = r16[e];
    }
    __syncthreads();
    if (tid < 16) {
        float s = 0.f;
        #pragma unroll
        for (int wv = 0; wv < WAVES_PB; ++wv) s += sh[wv][tid];
        // coherence-point store: no L2 dirty state, no fence needed
        __hip_atomic_store(&ws[(size_t)blockIdx.x * 16 + tid], s,
                           __ATOMIC_RELAXED, __HIP_MEMORY_SCOPE_AGENT);
    }

    // ---- two-level poison-relative ticket (relaxed atomics, no fences)
    __shared__ int isLast;
    __syncthreads();   // drains vmcnt(0): UC stores completed at coherence point
    if (tid == 0) {
        unsigned int* w32 = (unsigned int*)ws;
        const unsigned int base =
            __hip_atomic_load(w32 + BASE_DW, __ATOMIC_RELAXED, __HIP_MEMORY_SCOPE_AGENT);
        const int grp = blockIdx.x >> 4;               // /GPB, 0..15
        const unsigned int o1 =
            __hip_atomic_fetch_add(w32 + L1_DW + grp * 32, 1u,
                                   __ATOMIC_RELAXED, __HIP_MEMORY_SCOPE_AGENT);
        int last = 0;
        if (((o1 - base) & (unsigned int)(GPB - 1)) == (unsigned int)(GPB - 1)) {
            const unsigned int o2 =
                __hip_atomic_fetch_add(w32 + L2_DW, 1u,
                                       __ATOMIC_RELAXED, __HIP_MEMORY_SCOPE_AGENT);
            last = (((o2 - base) & (unsigned int)(GROUPS - 1)) == (unsigned int)(GROUPS - 1));
        }
        isLast = last;
    }
    __syncthreads();
    if (!isLast) return;

    // ---- last block: fold 256x16 partials -> 16 -> loss (UC loads)
    const int e = tid & 15;
    const int g = tid >> 4;             // 0..31
    float s2 = 0.f;
    #pragma unroll
    for (int m = 0; m < GRID / 32; ++m)            // 8 coalesced strided loads
        s2 += __hip_atomic_load(&ws[(size_t)(g + m * 32) * 16 + e],
                                __ATOMIC_RELAXED, __HIP_MEMORY_SCOPE_AGENT);

    __shared__ float acc2[32][17];
    acc2[g][e] = s2;
    __syncthreads();

    __shared__ float sums[16];
    if (tid < 16) {
        float t = 0.f;
        #pragma unroll
        for (int g2 = 0; g2 < 32; ++g2) t += acc2[g2][tid];
        sums[tid] = t;
    }
    __syncthreads();
    if (tid == 0) {
        float loss = (float)NCLS;
        #pragma unroll
        for (int t = 0; t < NCLS; ++t) loss -= sums[t] / sums[NCLS + t];
        out[0] = loss;
    }
}

extern "C" void kernel_launch(void* const* d_in, const int* in_sizes, int n_in,
                              void* d_out, int out_size, void* d_ws, size_t ws_size,
                              hipStream_t stream) {
    const float* f = (const float*)d_in[0];   // patch, 8192 fp32
    const float* P = (const float*)d_in[1];   // prob, 8192x8 fp32
    // d_in[2] is k==8 (compile-time constant here)

    sncut_fused<<<GRID, TPB, 0, stream>>>(f, P, (float*)d_ws, (float*)d_out);
}